// Round 15
// baseline (10172.642 us; speedup 1.0000x reference)
//
#include <hip/hip_runtime.h>
#include <hip/hip_bf16.h>
#include <math.h>

// ---------------------------------------------------------------------------
// MyRNN persistent kernel, round 15: r14 + conflict-free LDS staging + late
// wake (7P/8).
//   - staging remap: lane l stages dword pairs (2l, 2l+1) and (128+2l, ...):
//     LDS writes at 16B/lane stride -> zero bank conflicts (was 6.7e7).
//   - quiet-wake at tprev + 7P/8: ~1 pre-arrival poll instead of ~4; cuts
//     MALL poll pressure that queue-delays publishes.
//   Everything else = r14: fused xp, DPP reduces, fast tanh, 1-bit generation
//   tags in bf16 bit14, 2 rows/dword, 8 waves x 2 rows, fire-and-forget
//   publish, one barrier/step.
//
// ws layout (32-bit words):
//   [1024,3072)  hb0: 2048 packed dwords (h rows 2d,2d+1) - even t
//   [3072,5120)  hb1: same, odd t  (memset BYTE 0x40 -> gen-1 stale)
// hb0 memset 0 (h_0 = 0, gen 0); hb1 memset 0x40 every launch.
// ---------------------------------------------------------------------------

#define T_STEPS  2048
#define INPUT_N  2048
#define HIDDEN_N 4096
#define NWG      256
#define NTHR     512
#define TAGM32   0x40004000u

typedef float f32x4 __attribute__((ext_vector_type(4)));
typedef unsigned int uint32;
typedef unsigned long long u64;
typedef unsigned short u16;

__device__ __forceinline__ float bits_to_f(uint32 u) {
  union { uint32 u; float f; } c; c.u = u; return c.f;
}

// tanh via hardware exp+rcp: exact at 0 and +-inf; ~1e-6 abs error.
__device__ __forceinline__ float fast_tanh(float x) {
  float e = __expf(2.f * x);
  return 1.f - 2.f * __builtin_amdgcn_rcpf(e + 1.f);
}

// 64-lane sum via DPP; result valid on lane 63.
__device__ __forceinline__ float dpp_reduce63(float v) {
  int r;
  r = __builtin_amdgcn_update_dpp(0, __float_as_int(v), 0x111, 0xf, 0xf, true);
  v += __int_as_float(r);   // row_shr:1
  r = __builtin_amdgcn_update_dpp(0, __float_as_int(v), 0x112, 0xf, 0xf, true);
  v += __int_as_float(r);   // row_shr:2
  r = __builtin_amdgcn_update_dpp(0, __float_as_int(v), 0x114, 0xf, 0xf, true);
  v += __int_as_float(r);   // row_shr:4
  r = __builtin_amdgcn_update_dpp(0, __float_as_int(v), 0x118, 0xf, 0xf, true);
  v += __int_as_float(r);   // row_shr:8  -> lane15 of each row = row sum
  r = __builtin_amdgcn_update_dpp(0, __float_as_int(v), 0x142, 0xf, 0xf, true);
  v += __int_as_float(r);   // row_bcast:15
  r = __builtin_amdgcn_update_dpp(0, __float_as_int(v), 0x143, 0xf, 0xf, true);
  v += __int_as_float(r);   // row_bcast:31 -> lane63 = total
  return v;
}

__global__ __attribute__((amdgpu_flat_work_group_size(512, 512)))
__attribute__((amdgpu_waves_per_eu(2))) void rnn_persistent(
    const float* __restrict__ x,
    const float* __restrict__ wh_w, const float* __restrict__ wh_b,
    const float* __restrict__ wx_w, const float* __restrict__ wx_b,
    const float* __restrict__ wo_w, const float* __restrict__ wo_b,
    float* __restrict__ out, float* __restrict__ ws) {
  const int w    = blockIdx.x;    // owns hidden rows [16w, 16w+16)
  const int tid  = threadIdx.x;   // 0..511
  const int lane = tid & 63;
  const int wv   = tid >> 6;      // wave 0..7 owns rows 16w+2wv, 16w+2wv+1

  uint32* hb0 = (uint32*)(ws + 1024);   // 2048 packed dwords
  uint32* hb1 = (uint32*)(ws + 3072);

  __shared__ float s_h[HIDDEN_N];   // 16 KiB staged h (f32)

  // ---------------- resident weights ---------------------------------------
  const int r0 = w * 16 + 2 * wv;
  const float* wr0 = wh_w + (size_t)r0 * HIDDEN_N + lane * 4;
  const float* wr1 = wh_w + (size_t)(r0 + 1) * HIDDEN_N + lane * 4;
  f32x4 W0[16], W1[16];
#pragma unroll
  for (int i = 0; i < 16; ++i) {
    W0[i] = *(const f32x4*)(wr0 + i * 256);
    W1[i] = *(const f32x4*)(wr1 + i * 256);
  }
  const float* xr0 = wx_w + (size_t)r0 * INPUT_N + lane * 4;
  const float* xr1 = wx_w + (size_t)(r0 + 1) * INPUT_N + lane * 4;
  f32x4 WX0[8], WX1[8];
#pragma unroll
  for (int j = 0; j < 8; ++j) {
    WX0[j] = *(const f32x4*)(xr0 + j * 256);
    WX1[j] = *(const f32x4*)(xr1 + j * 256);
  }
  const float bB0 = wh_b[r0], bB1 = wh_b[r0 + 1];
  const float bA0 = wx_b[r0], bA1 = wx_b[r0 + 1];
  // conflict-free staging map: lane stages dword pairs cb1=(2l,2l+1) and
  // cb2=(128+2l,129+2l); LDS writes land at 16B/lane stride.
  const int   cb1   = wv * 256 + 2 * lane;
  const int   cb2   = cb1 + 128;
  const int   pidx  = w * 8 + wv;            // my publish dword
  const u64   M64   = 0x4000400040004000ull;

  // xp(t) for this wave's 2 rows, all lanes (DPP reduce + bcast from 63)
  auto compute_xp = [&](int tt) -> float2 {
    const float* xrow = x + (size_t)tt * INPUT_N + lane * 4;
    f32x4 a = {0.f, 0.f, 0.f, 0.f}, b = {0.f, 0.f, 0.f, 0.f};
#pragma unroll
    for (int j = 0; j < 8; ++j) {
      f32x4 xv = *(const f32x4*)(xrow + j * 256);
      a += xv * WX0[j];
      b += xv * WX1[j];
    }
    float ra = dpp_reduce63(a.x + a.y + a.z + a.w);
    float rb = dpp_reduce63(b.x + b.y + b.z + b.w);
    float2 res;
    res.x = __shfl(ra, 63) + bA0;
    res.y = __shfl(rb, 63) + bA1;
    return res;
  };

  // wave-uniform timing state (SALU): EMA of detect-to-detect period
  u64    tprev = 0;
  uint32 P     = 0;

  auto step = [&](int t, const uint32* hbsrc, uint32* hbdst, u64 expv,
                  uint32 pubtag, float2 xpv) {
    // 1) quiet wait until ~7/8 of predicted period elapsed (no mem traffic;
    //    late wake costs nothing -- data already there, first poll hits)
    if (t >= 4 && P > 0) {
      const u64 target = tprev + (u64)(P - (P >> 3));
      while (__builtin_amdgcn_s_memrealtime() < target)
        __builtin_amdgcn_s_sleep(2);
    }
    // 2) tag-poll + stage my 4 dwords of h_t (64cy retry quantum)
    const uint32* s1 = hbsrc + cb1;
    const uint32* s2 = hbsrc + cb2;
    u64 u01 = 0, u23 = 0;
    {
      bool d0 = false, d1 = false;
      for (;;) {
        if (!d0) {
          u01 = __hip_atomic_load((const u64*)s1, __ATOMIC_RELAXED,
                                  __HIP_MEMORY_SCOPE_AGENT);
          d0 = (u01 & M64) == expv;
        }
        if (!d1) {
          u23 = __hip_atomic_load((const u64*)s2, __ATOMIC_RELAXED,
                                  __HIP_MEMORY_SCOPE_AGENT);
          d1 = (u23 & M64) == expv;
        }
        if (__all(d0 && d1)) break;
        __builtin_amdgcn_s_sleep(1);
      }
    }
    const u64 tnow = __builtin_amdgcn_s_memrealtime();   // capture only
    // 3) unpack (clear tag bits) -> LDS, conflict-free (16B/lane stride)
    {
      uint32 w0 = (uint32)u01 & ~TAGM32, w1 = (uint32)(u01 >> 32) & ~TAGM32;
      uint32 w2 = (uint32)u23 & ~TAGM32, w3 = (uint32)(u23 >> 32) & ~TAGM32;
      f32x4 pa, pb;
      pa.x = bits_to_f(w0 << 16);  pa.y = bits_to_f(w0 & 0xffff0000u);
      pa.z = bits_to_f(w1 << 16);  pa.w = bits_to_f(w1 & 0xffff0000u);
      pb.x = bits_to_f(w2 << 16);  pb.y = bits_to_f(w2 & 0xffff0000u);
      pb.z = bits_to_f(w3 << 16);  pb.w = bits_to_f(w3 & 0xffff0000u);
      *(f32x4*)&s_h[2 * cb1] = pa;
      *(f32x4*)&s_h[2 * cb2] = pb;
    }
    // 4) EMA update (overlaps straggler waves' detect; off the hot path)
    {
      u64 dt64 = tnow - tprev;
      if (t > 0 && dt64 < (1ull << 20)) {
        uint32 dt = (uint32)dt64;
        P = P ? ((P * 3 + dt) >> 2) : dt;
      }
      tprev = tnow;
    }
    __syncthreads();
    // 5) 2-row dot from LDS against resident Wh
    f32x4 a = {0.f, 0.f, 0.f, 0.f}, b = {0.f, 0.f, 0.f, 0.f};
#pragma unroll
    for (int i = 0; i < 16; ++i) {
      f32x4 hv = *(const f32x4*)&s_h[lane * 4 + i * 256];
      a += hv * W0[i];
      b += hv * W1[i];
    }
    float ra = __shfl(dpp_reduce63(a.x + a.y + a.z + a.w), 63);
    float rb = __shfl(dpp_reduce63(b.x + b.y + b.z + b.w), 63);
    // 6) fast tanh on lanes 0,1 in parallel; lane0 packs + publishes
    float pre = (lane == 0) ? (ra + bB0 + xpv.x) : (rb + bB1 + xpv.y);
    float hn  = fast_tanh(pre);
    float h1v = __shfl(hn, 1);
    if (lane == 0) {
      __hip_bfloat16 c0 = __float2bfloat16(hn);
      __hip_bfloat16 c1 = __float2bfloat16(h1v);
      uint32 word = (uint32)(*(u16*)&c0) | ((uint32)(*(u16*)&c1) << 16);
      word |= pubtag;
      __hip_atomic_store(hbdst + pidx, word, __ATOMIC_RELAXED,
                         __HIP_MEMORY_SCOPE_AGENT);    // fire-and-forget
    }
  };

  // ---------------- prologue: xp ring for t=0,1 ----------------------------
  float2 xpA = compute_xp(0);
  float2 xpB = compute_xp(1);

  // ---------------- the scan (unrolled x2: static ring/parity) -------------
  for (int t2 = 0; t2 < T_STEPS; t2 += 2) {
    const int g = (t2 >> 1) & 1;             // generation of h_t2 and h_{t2+1}
    const u64   expv  = g ? M64 : 0ull;
    const uint32 tagA = g ? TAGM32 : 0u;     // h_{t2+1} carries gen g
    const uint32 tagB = g ? 0u : TAGM32;     // h_{t2+2} carries gen !g

    step(t2,     hb0, hb1, expv, tagA, xpA);
    if (t2 + 2 < T_STEPS) xpA = compute_xp(t2 + 2);
    step(t2 + 1, hb1, hb0, expv, tagB, xpB);
    if (t2 + 3 < T_STEPS) xpB = compute_xp(t2 + 3);
  }

  // ---------------- output: sigmoid(hT @ Wo^T + bo) ------------------------
  {
    // h_2048: buffer hb0 (2048&1=0), generation (2048>>1)&1 = 0
    const uint32* s1 = hb0 + cb1;
    const uint32* s2 = hb0 + cb2;
    u64 u01 = 0, u23 = 0;
    bool d0 = false, d1 = false;
    for (;;) {
      if (!d0) {
        u01 = __hip_atomic_load((const u64*)s1, __ATOMIC_RELAXED,
                                __HIP_MEMORY_SCOPE_AGENT);
        d0 = (u01 & M64) == 0ull;
      }
      if (!d1) {
        u23 = __hip_atomic_load((const u64*)s2, __ATOMIC_RELAXED,
                                __HIP_MEMORY_SCOPE_AGENT);
        d1 = (u23 & M64) == 0ull;
      }
      if (__all(d0 && d1)) break;
      __builtin_amdgcn_s_sleep(1);
    }
    uint32 w0 = (uint32)u01 & ~TAGM32, w1 = (uint32)(u01 >> 32) & ~TAGM32;
    uint32 w2 = (uint32)u23 & ~TAGM32, w3 = (uint32)(u23 >> 32) & ~TAGM32;
    f32x4 pa, pb;
    pa.x = bits_to_f(w0 << 16);  pa.y = bits_to_f(w0 & 0xffff0000u);
    pa.z = bits_to_f(w1 << 16);  pa.w = bits_to_f(w1 & 0xffff0000u);
    pb.x = bits_to_f(w2 << 16);  pb.y = bits_to_f(w2 & 0xffff0000u);
    pb.z = bits_to_f(w3 << 16);  pb.w = bits_to_f(w3 & 0xffff0000u);
    *(f32x4*)&s_h[2 * cb1] = pa;
    *(f32x4*)&s_h[2 * cb2] = pb;
  }
  __syncthreads();
  {
    const int o = w * 8 + wv;     // 8 outputs per WG, one per wave
    const float* worow = wo_w + (size_t)o * HIDDEN_N + lane * 4;
    f32x4 acc = {0.f, 0.f, 0.f, 0.f};
#pragma unroll
    for (int k = 0; k < 16; ++k)
      acc += (*(const f32x4*)(worow + k * 256)) *
             (*(const f32x4*)&s_h[lane * 4 + k * 256]);
    float s = __shfl(dpp_reduce63(acc.x + acc.y + acc.z + acc.w), 63);
    if (lane == 0) {
      float z = s + wo_b[o];
      out[o] = 1.f / (1.f + expf(-z));
    }
  }
}

extern "C" void kernel_launch(void* const* d_in, const int* in_sizes, int n_in,
                              void* d_out, int out_size, void* d_ws,
                              size_t ws_size, hipStream_t stream) {
  const float* x    = (const float*)d_in[0];
  const float* wh_w = (const float*)d_in[1];
  const float* wh_b = (const float*)d_in[2];
  const float* wx_w = (const float*)d_in[3];
  const float* wx_b = (const float*)d_in[4];
  const float* wo_w = (const float*)d_in[5];
  const float* wo_b = (const float*)d_in[6];
  float* out = (float*)d_out;
  float* ws  = (float*)d_ws;

  // hb0 = 0x00 (h_0 = 0, generation 0, immediately valid at t=0);
  // hb1 = 0x40 bytes (generation-1 stale marker for t=1's gen-0 wait).
  hipMemsetAsync((char*)d_ws + 1024 * 4, 0x00, 2048 * 4, stream);
  hipMemsetAsync((char*)d_ws + 3072 * 4, 0x40, 2048 * 4, stream);

  hipLaunchKernelGGL(rnn_persistent, dim3(NWG), dim3(NTHR), 0, stream,
                     x, wh_w, wh_b, wx_w, wx_b, wo_w, wo_b, out, ws);
}

// Round 16
// 7171.017 us; speedup vs baseline: 1.4186x; 1.4186x over previous
//
#include <hip/hip_runtime.h>
#include <hip/hip_bf16.h>
#include <math.h>

// ---------------------------------------------------------------------------
// MyRNN persistent kernel, round 16: r14 timing (wake P/2, stable) +
// r15's conflict-free LDS staging (the proven-good half).
//   r15 lesson: wake at 7P/8 made the sleep the pacemaker (detect driven by
//   wake, publish slips, EMA absorbs the slip -> P* = 8C inflation). Wake at
//   P/2 keeps detect arrival-driven -> stable. Keep it.
//   - staging remap: lane l stages dword pairs (2l,2l+1),(128+2l,129+2l):
//     16B/lane LDS stride -> zero bank conflicts (verified r15).
//   - fused xp (no phase A), DPP reduces, fast tanh, 1-bit generation tags
//     in bf16 bit14, 2 rows/dword, 8 waves x 2 rows, fire-and-forget publish,
//     one barrier/step.
//
// ws layout (32-bit words):
//   [1024,3072)  hb0: 2048 packed dwords (h rows 2d,2d+1) - even t
//   [3072,5120)  hb1: same, odd t  (memset BYTE 0x40 -> gen-1 stale)
// hb0 memset 0 (h_0 = 0, gen 0); hb1 memset 0x40 every launch.
// ---------------------------------------------------------------------------

#define T_STEPS  2048
#define INPUT_N  2048
#define HIDDEN_N 4096
#define NWG      256
#define NTHR     512
#define TAGM32   0x40004000u

typedef float f32x4 __attribute__((ext_vector_type(4)));
typedef unsigned int uint32;
typedef unsigned long long u64;
typedef unsigned short u16;

__device__ __forceinline__ float bits_to_f(uint32 u) {
  union { uint32 u; float f; } c; c.u = u; return c.f;
}

// tanh via hardware exp+rcp: exact at 0 and +-inf; ~1e-6 abs error.
__device__ __forceinline__ float fast_tanh(float x) {
  float e = __expf(2.f * x);
  return 1.f - 2.f * __builtin_amdgcn_rcpf(e + 1.f);
}

// 64-lane sum via DPP; result valid on lane 63.
__device__ __forceinline__ float dpp_reduce63(float v) {
  int r;
  r = __builtin_amdgcn_update_dpp(0, __float_as_int(v), 0x111, 0xf, 0xf, true);
  v += __int_as_float(r);   // row_shr:1
  r = __builtin_amdgcn_update_dpp(0, __float_as_int(v), 0x112, 0xf, 0xf, true);
  v += __int_as_float(r);   // row_shr:2
  r = __builtin_amdgcn_update_dpp(0, __float_as_int(v), 0x114, 0xf, 0xf, true);
  v += __int_as_float(r);   // row_shr:4
  r = __builtin_amdgcn_update_dpp(0, __float_as_int(v), 0x118, 0xf, 0xf, true);
  v += __int_as_float(r);   // row_shr:8  -> lane15 of each row = row sum
  r = __builtin_amdgcn_update_dpp(0, __float_as_int(v), 0x142, 0xf, 0xf, true);
  v += __int_as_float(r);   // row_bcast:15
  r = __builtin_amdgcn_update_dpp(0, __float_as_int(v), 0x143, 0xf, 0xf, true);
  v += __int_as_float(r);   // row_bcast:31 -> lane63 = total
  return v;
}

__global__ __attribute__((amdgpu_flat_work_group_size(512, 512)))
__attribute__((amdgpu_waves_per_eu(2))) void rnn_persistent(
    const float* __restrict__ x,
    const float* __restrict__ wh_w, const float* __restrict__ wh_b,
    const float* __restrict__ wx_w, const float* __restrict__ wx_b,
    const float* __restrict__ wo_w, const float* __restrict__ wo_b,
    float* __restrict__ out, float* __restrict__ ws) {
  const int w    = blockIdx.x;    // owns hidden rows [16w, 16w+16)
  const int tid  = threadIdx.x;   // 0..511
  const int lane = tid & 63;
  const int wv   = tid >> 6;      // wave 0..7 owns rows 16w+2wv, 16w+2wv+1

  uint32* hb0 = (uint32*)(ws + 1024);   // 2048 packed dwords
  uint32* hb1 = (uint32*)(ws + 3072);

  __shared__ float s_h[HIDDEN_N];   // 16 KiB staged h (f32)

  // ---------------- resident weights ---------------------------------------
  const int r0 = w * 16 + 2 * wv;
  const float* wr0 = wh_w + (size_t)r0 * HIDDEN_N + lane * 4;
  const float* wr1 = wh_w + (size_t)(r0 + 1) * HIDDEN_N + lane * 4;
  f32x4 W0[16], W1[16];
#pragma unroll
  for (int i = 0; i < 16; ++i) {
    W0[i] = *(const f32x4*)(wr0 + i * 256);
    W1[i] = *(const f32x4*)(wr1 + i * 256);
  }
  const float* xr0 = wx_w + (size_t)r0 * INPUT_N + lane * 4;
  const float* xr1 = wx_w + (size_t)(r0 + 1) * INPUT_N + lane * 4;
  f32x4 WX0[8], WX1[8];
#pragma unroll
  for (int j = 0; j < 8; ++j) {
    WX0[j] = *(const f32x4*)(xr0 + j * 256);
    WX1[j] = *(const f32x4*)(xr1 + j * 256);
  }
  const float bB0 = wh_b[r0], bB1 = wh_b[r0 + 1];
  const float bA0 = wx_b[r0], bA1 = wx_b[r0 + 1];
  // conflict-free staging map: 16B/lane LDS stride (r15-verified, 0 conflicts)
  const int   cb1   = wv * 256 + 2 * lane;
  const int   cb2   = cb1 + 128;
  const int   pidx  = w * 8 + wv;            // my publish dword
  const u64   M64   = 0x4000400040004000ull;

  // xp(t) for this wave's 2 rows, all lanes (DPP reduce + bcast from 63)
  auto compute_xp = [&](int tt) -> float2 {
    const float* xrow = x + (size_t)tt * INPUT_N + lane * 4;
    f32x4 a = {0.f, 0.f, 0.f, 0.f}, b = {0.f, 0.f, 0.f, 0.f};
#pragma unroll
    for (int j = 0; j < 8; ++j) {
      f32x4 xv = *(const f32x4*)(xrow + j * 256);
      a += xv * WX0[j];
      b += xv * WX1[j];
    }
    float ra = dpp_reduce63(a.x + a.y + a.z + a.w);
    float rb = dpp_reduce63(b.x + b.y + b.z + b.w);
    float2 res;
    res.x = __shfl(ra, 63) + bA0;
    res.y = __shfl(rb, 63) + bA1;
    return res;
  };

  // wave-uniform timing state (SALU): EMA of detect-to-detect period
  u64    tprev = 0;
  uint32 P     = 0;

  auto step = [&](int t, const uint32* hbsrc, uint32* hbdst, u64 expv,
                  uint32 pubtag, float2 xpv) {
    // 1) quiet wait until ~1/2 of predicted period (ARRIVAL-DRIVEN detect:
    //    wake must always precede arrival -- r15's 7P/8 self-paced unstably)
    if (t >= 4 && P > 0) {
      const u64 target = tprev + (u64)(P >> 1);
      while (__builtin_amdgcn_s_memrealtime() < target)
        __builtin_amdgcn_s_sleep(2);
    }
    // 2) tag-poll + stage my 4 dwords of h_t (64cy retry quantum)
    const uint32* s1 = hbsrc + cb1;
    const uint32* s2 = hbsrc + cb2;
    u64 u01 = 0, u23 = 0;
    {
      bool d0 = false, d1 = false;
      for (;;) {
        if (!d0) {
          u01 = __hip_atomic_load((const u64*)s1, __ATOMIC_RELAXED,
                                  __HIP_MEMORY_SCOPE_AGENT);
          d0 = (u01 & M64) == expv;
        }
        if (!d1) {
          u23 = __hip_atomic_load((const u64*)s2, __ATOMIC_RELAXED,
                                  __HIP_MEMORY_SCOPE_AGENT);
          d1 = (u23 & M64) == expv;
        }
        if (__all(d0 && d1)) break;
        __builtin_amdgcn_s_sleep(1);
      }
    }
    const u64 tnow = __builtin_amdgcn_s_memrealtime();   // capture only
    // 3) unpack (clear tag bits) -> LDS, conflict-free (16B/lane stride)
    {
      uint32 w0 = (uint32)u01 & ~TAGM32, w1 = (uint32)(u01 >> 32) & ~TAGM32;
      uint32 w2 = (uint32)u23 & ~TAGM32, w3 = (uint32)(u23 >> 32) & ~TAGM32;
      f32x4 pa, pb;
      pa.x = bits_to_f(w0 << 16);  pa.y = bits_to_f(w0 & 0xffff0000u);
      pa.z = bits_to_f(w1 << 16);  pa.w = bits_to_f(w1 & 0xffff0000u);
      pb.x = bits_to_f(w2 << 16);  pb.y = bits_to_f(w2 & 0xffff0000u);
      pb.z = bits_to_f(w3 << 16);  pb.w = bits_to_f(w3 & 0xffff0000u);
      *(f32x4*)&s_h[2 * cb1] = pa;
      *(f32x4*)&s_h[2 * cb2] = pb;
    }
    // 4) EMA update (off the hot path; overlaps straggler waves' detect)
    {
      u64 dt64 = tnow - tprev;
      if (t > 0 && dt64 < (1ull << 20)) {
        uint32 dt = (uint32)dt64;
        P = P ? ((P * 3 + dt) >> 2) : dt;
      }
      tprev = tnow;
    }
    __syncthreads();
    // 5) 2-row dot from LDS against resident Wh
    f32x4 a = {0.f, 0.f, 0.f, 0.f}, b = {0.f, 0.f, 0.f, 0.f};
#pragma unroll
    for (int i = 0; i < 16; ++i) {
      f32x4 hv = *(const f32x4*)&s_h[lane * 4 + i * 256];
      a += hv * W0[i];
      b += hv * W1[i];
    }
    float ra = __shfl(dpp_reduce63(a.x + a.y + a.z + a.w), 63);
    float rb = __shfl(dpp_reduce63(b.x + b.y + b.z + b.w), 63);
    // 6) fast tanh on lanes 0,1 in parallel; lane0 packs + publishes
    float pre = (lane == 0) ? (ra + bB0 + xpv.x) : (rb + bB1 + xpv.y);
    float hn  = fast_tanh(pre);
    float h1v = __shfl(hn, 1);
    if (lane == 0) {
      __hip_bfloat16 c0 = __float2bfloat16(hn);
      __hip_bfloat16 c1 = __float2bfloat16(h1v);
      uint32 word = (uint32)(*(u16*)&c0) | ((uint32)(*(u16*)&c1) << 16);
      word |= pubtag;
      __hip_atomic_store(hbdst + pidx, word, __ATOMIC_RELAXED,
                         __HIP_MEMORY_SCOPE_AGENT);    // fire-and-forget
    }
  };

  // ---------------- prologue: xp ring for t=0,1 ----------------------------
  float2 xpA = compute_xp(0);
  float2 xpB = compute_xp(1);

  // ---------------- the scan (unrolled x2: static ring/parity) -------------
  for (int t2 = 0; t2 < T_STEPS; t2 += 2) {
    const int g = (t2 >> 1) & 1;             // generation of h_t2 and h_{t2+1}
    const u64   expv  = g ? M64 : 0ull;
    const uint32 tagA = g ? TAGM32 : 0u;     // h_{t2+1} carries gen g
    const uint32 tagB = g ? 0u : TAGM32;     // h_{t2+2} carries gen !g

    step(t2,     hb0, hb1, expv, tagA, xpA);
    if (t2 + 2 < T_STEPS) xpA = compute_xp(t2 + 2);
    step(t2 + 1, hb1, hb0, expv, tagB, xpB);
    if (t2 + 3 < T_STEPS) xpB = compute_xp(t2 + 3);
  }

  // ---------------- output: sigmoid(hT @ Wo^T + bo) ------------------------
  {
    // h_2048: buffer hb0 (2048&1=0), generation (2048>>1)&1 = 0
    const uint32* s1 = hb0 + cb1;
    const uint32* s2 = hb0 + cb2;
    u64 u01 = 0, u23 = 0;
    bool d0 = false, d1 = false;
    for (;;) {
      if (!d0) {
        u01 = __hip_atomic_load((const u64*)s1, __ATOMIC_RELAXED,
                                __HIP_MEMORY_SCOPE_AGENT);
        d0 = (u01 & M64) == 0ull;
      }
      if (!d1) {
        u23 = __hip_atomic_load((const u64*)s2, __ATOMIC_RELAXED,
                                __HIP_MEMORY_SCOPE_AGENT);
        d1 = (u23 & M64) == 0ull;
      }
      if (__all(d0 && d1)) break;
      __builtin_amdgcn_s_sleep(1);
    }
    uint32 w0 = (uint32)u01 & ~TAGM32, w1 = (uint32)(u01 >> 32) & ~TAGM32;
    uint32 w2 = (uint32)u23 & ~TAGM32, w3 = (uint32)(u23 >> 32) & ~TAGM32;
    f32x4 pa, pb;
    pa.x = bits_to_f(w0 << 16);  pa.y = bits_to_f(w0 & 0xffff0000u);
    pa.z = bits_to_f(w1 << 16);  pa.w = bits_to_f(w1 & 0xffff0000u);
    pb.x = bits_to_f(w2 << 16);  pb.y = bits_to_f(w2 & 0xffff0000u);
    pb.z = bits_to_f(w3 << 16);  pb.w = bits_to_f(w3 & 0xffff0000u);
    *(f32x4*)&s_h[2 * cb1] = pa;
    *(f32x4*)&s_h[2 * cb2] = pb;
  }
  __syncthreads();
  {
    const int o = w * 8 + wv;     // 8 outputs per WG, one per wave
    const float* worow = wo_w + (size_t)o * HIDDEN_N + lane * 4;
    f32x4 acc = {0.f, 0.f, 0.f, 0.f};
#pragma unroll
    for (int k = 0; k < 16; ++k)
      acc += (*(const f32x4*)(worow + k * 256)) *
             (*(const f32x4*)&s_h[lane * 4 + k * 256]);
    float s = __shfl(dpp_reduce63(acc.x + acc.y + acc.z + acc.w), 63);
    if (lane == 0) {
      float z = s + wo_b[o];
      out[o] = 1.f / (1.f + expf(-z));
    }
  }
}

extern "C" void kernel_launch(void* const* d_in, const int* in_sizes, int n_in,
                              void* d_out, int out_size, void* d_ws,
                              size_t ws_size, hipStream_t stream) {
  const float* x    = (const float*)d_in[0];
  const float* wh_w = (const float*)d_in[1];
  const float* wh_b = (const float*)d_in[2];
  const float* wx_w = (const float*)d_in[3];
  const float* wx_b = (const float*)d_in[4];
  const float* wo_w = (const float*)d_in[5];
  const float* wo_b = (const float*)d_in[6];
  float* out = (float*)d_out;
  float* ws  = (float*)d_ws;

  // hb0 = 0x00 (h_0 = 0, generation 0, immediately valid at t=0);
  // hb1 = 0x40 bytes (generation-1 stale marker for t=1's gen-0 wait).
  hipMemsetAsync((char*)d_ws + 1024 * 4, 0x00, 2048 * 4, stream);
  hipMemsetAsync((char*)d_ws + 3072 * 4, 0x40, 2048 * 4, stream);

  hipLaunchKernelGGL(rnn_persistent, dim3(NWG), dim3(NTHR), 0, stream,
                     x, wh_w, wh_b, wx_w, wx_b, wo_w, wo_b, out, ws);
}

// Round 17
// 6792.586 us; speedup vs baseline: 1.4976x; 1.0557x over previous
//
#include <hip/hip_runtime.h>
#include <hip/hip_bf16.h>
#include <math.h>

// ---------------------------------------------------------------------------
// MyRNN persistent kernel, round 17 == round 14 exactly (best measured:
// 6846 us). Confirmation/lock-in run for the sync-latency floor.
//   - fused xp (no phase A), DPP reduces, fast tanh (exp+rcp)
//   - 1-bit generation tags in bf16 bit14, 2 rows/dword, 8 waves x 2 rows
//   - EMA timed quiet-wait, wake at tprev + P/2 (arrival-driven detect;
//     7P/8 is unstable - the sleep becomes the pacemaker, r15)
//   - fire-and-forget tagged publish; one barrier/step
//   Cross-family evidence says ~3.3 us/step is this chip's floor for a
//   2048-long serialized all-to-all broadcast chain: publish->MALL ~0.5us +
//   detect RT ~0.8us + unpack/barrier ~0.15us + dot/reduce/tanh ~0.4us +
//   straggler-max(256 WGs) ~1us.
//
// ws layout (32-bit words):
//   [1024,3072)  hb0: 2048 packed dwords (h rows 2d,2d+1) - even t
//   [3072,5120)  hb1: same, odd t  (memset BYTE 0x40 -> gen-1 stale)
// hb0 memset 0 (h_0 = 0, gen 0); hb1 memset 0x40 every launch.
// ---------------------------------------------------------------------------

#define T_STEPS  2048
#define INPUT_N  2048
#define HIDDEN_N 4096
#define NWG      256
#define NTHR     512
#define TAGM32   0x40004000u

typedef float f32x4 __attribute__((ext_vector_type(4)));
typedef unsigned int uint32;
typedef unsigned long long u64;
typedef unsigned short u16;

__device__ __forceinline__ float bits_to_f(uint32 u) {
  union { uint32 u; float f; } c; c.u = u; return c.f;
}

// tanh via hardware exp+rcp: exact at 0 and +-inf; ~1e-6 abs error.
__device__ __forceinline__ float fast_tanh(float x) {
  float e = __expf(2.f * x);
  return 1.f - 2.f * __builtin_amdgcn_rcpf(e + 1.f);
}

// 64-lane sum via DPP; result valid on lane 63.
__device__ __forceinline__ float dpp_reduce63(float v) {
  int r;
  r = __builtin_amdgcn_update_dpp(0, __float_as_int(v), 0x111, 0xf, 0xf, true);
  v += __int_as_float(r);   // row_shr:1
  r = __builtin_amdgcn_update_dpp(0, __float_as_int(v), 0x112, 0xf, 0xf, true);
  v += __int_as_float(r);   // row_shr:2
  r = __builtin_amdgcn_update_dpp(0, __float_as_int(v), 0x114, 0xf, 0xf, true);
  v += __int_as_float(r);   // row_shr:4
  r = __builtin_amdgcn_update_dpp(0, __float_as_int(v), 0x118, 0xf, 0xf, true);
  v += __int_as_float(r);   // row_shr:8  -> lane15 of each row = row sum
  r = __builtin_amdgcn_update_dpp(0, __float_as_int(v), 0x142, 0xf, 0xf, true);
  v += __int_as_float(r);   // row_bcast:15
  r = __builtin_amdgcn_update_dpp(0, __float_as_int(v), 0x143, 0xf, 0xf, true);
  v += __int_as_float(r);   // row_bcast:31 -> lane63 = total
  return v;
}

__global__ __attribute__((amdgpu_flat_work_group_size(512, 512)))
__attribute__((amdgpu_waves_per_eu(2))) void rnn_persistent(
    const float* __restrict__ x,
    const float* __restrict__ wh_w, const float* __restrict__ wh_b,
    const float* __restrict__ wx_w, const float* __restrict__ wx_b,
    const float* __restrict__ wo_w, const float* __restrict__ wo_b,
    float* __restrict__ out, float* __restrict__ ws) {
  const int w    = blockIdx.x;    // owns hidden rows [16w, 16w+16)
  const int tid  = threadIdx.x;   // 0..511
  const int lane = tid & 63;
  const int wv   = tid >> 6;      // wave 0..7 owns rows 16w+2wv, 16w+2wv+1

  uint32* hb0 = (uint32*)(ws + 1024);   // 2048 packed dwords
  uint32* hb1 = (uint32*)(ws + 3072);

  __shared__ float s_h[HIDDEN_N];   // 16 KiB staged h (f32)

  // ---------------- resident weights ---------------------------------------
  const int r0 = w * 16 + 2 * wv;
  const float* wr0 = wh_w + (size_t)r0 * HIDDEN_N + lane * 4;
  const float* wr1 = wh_w + (size_t)(r0 + 1) * HIDDEN_N + lane * 4;
  f32x4 W0[16], W1[16];
#pragma unroll
  for (int i = 0; i < 16; ++i) {
    W0[i] = *(const f32x4*)(wr0 + i * 256);
    W1[i] = *(const f32x4*)(wr1 + i * 256);
  }
  const float* xr0 = wx_w + (size_t)r0 * INPUT_N + lane * 4;
  const float* xr1 = wx_w + (size_t)(r0 + 1) * INPUT_N + lane * 4;
  f32x4 WX0[8], WX1[8];
#pragma unroll
  for (int j = 0; j < 8; ++j) {
    WX0[j] = *(const f32x4*)(xr0 + j * 256);
    WX1[j] = *(const f32x4*)(xr1 + j * 256);
  }
  const float bB0 = wh_b[r0], bB1 = wh_b[r0 + 1];
  const float bA0 = wx_b[r0], bA1 = wx_b[r0 + 1];
  const int   cbase = wv * 256 + lane * 4;   // my 4 packed dwords
  const int   pidx  = w * 8 + wv;            // my publish dword
  const u64   M64   = 0x4000400040004000ull;

  // xp(t) for this wave's 2 rows, all lanes (DPP reduce + bcast from 63)
  auto compute_xp = [&](int tt) -> float2 {
    const float* xrow = x + (size_t)tt * INPUT_N + lane * 4;
    f32x4 a = {0.f, 0.f, 0.f, 0.f}, b = {0.f, 0.f, 0.f, 0.f};
#pragma unroll
    for (int j = 0; j < 8; ++j) {
      f32x4 xv = *(const f32x4*)(xrow + j * 256);
      a += xv * WX0[j];
      b += xv * WX1[j];
    }
    float ra = dpp_reduce63(a.x + a.y + a.z + a.w);
    float rb = dpp_reduce63(b.x + b.y + b.z + b.w);
    float2 res;
    res.x = __shfl(ra, 63) + bA0;
    res.y = __shfl(rb, 63) + bA1;
    return res;
  };

  // wave-uniform timing state (SALU): EMA of detect-to-detect period
  u64    tprev = 0;
  uint32 P     = 0;

  auto step = [&](int t, const uint32* hbsrc, uint32* hbdst, u64 expv,
                  uint32 pubtag, float2 xpv) {
    // 1) quiet wait until ~1/2 of predicted period elapsed (no mem traffic;
    //    wake early enough to keep detect arrival-driven)
    if (t >= 4 && P > 0) {
      const u64 target = tprev + (u64)(P >> 1);
      while (__builtin_amdgcn_s_memrealtime() < target)
        __builtin_amdgcn_s_sleep(2);
    }
    // 2) tag-poll + stage my 4 dwords of h_t (64cy retry quantum)
    const uint32* src = hbsrc + cbase;
    u64 u01 = 0, u23 = 0;
    {
      bool d0 = false, d1 = false;
      for (;;) {
        if (!d0) {
          u01 = __hip_atomic_load((const u64*)src, __ATOMIC_RELAXED,
                                  __HIP_MEMORY_SCOPE_AGENT);
          d0 = (u01 & M64) == expv;
        }
        if (!d1) {
          u23 = __hip_atomic_load((const u64*)(src + 2), __ATOMIC_RELAXED,
                                  __HIP_MEMORY_SCOPE_AGENT);
          d1 = (u23 & M64) == expv;
        }
        if (__all(d0 && d1)) break;
        __builtin_amdgcn_s_sleep(1);
      }
    }
    const u64 tnow = __builtin_amdgcn_s_memrealtime();   // capture only
    // 3) unpack (clear tag bits) -> LDS
    {
      uint32 w0 = (uint32)u01 & ~TAGM32, w1 = (uint32)(u01 >> 32) & ~TAGM32;
      uint32 w2 = (uint32)u23 & ~TAGM32, w3 = (uint32)(u23 >> 32) & ~TAGM32;
      f32x4 pa, pb;
      pa.x = bits_to_f(w0 << 16);  pa.y = bits_to_f(w0 & 0xffff0000u);
      pa.z = bits_to_f(w1 << 16);  pa.w = bits_to_f(w1 & 0xffff0000u);
      pb.x = bits_to_f(w2 << 16);  pb.y = bits_to_f(w2 & 0xffff0000u);
      pb.z = bits_to_f(w3 << 16);  pb.w = bits_to_f(w3 & 0xffff0000u);
      *(f32x4*)&s_h[2 * cbase]     = pa;
      *(f32x4*)&s_h[2 * cbase + 4] = pb;
    }
    // 4) EMA update (overlaps straggler waves' detect; off the hot path)
    {
      u64 dt64 = tnow - tprev;
      if (t > 0 && dt64 < (1ull << 20)) {
        uint32 dt = (uint32)dt64;
        P = P ? ((P * 3 + dt) >> 2) : dt;
      }
      tprev = tnow;
    }
    __syncthreads();
    // 5) 2-row dot from LDS against resident Wh
    f32x4 a = {0.f, 0.f, 0.f, 0.f}, b = {0.f, 0.f, 0.f, 0.f};
#pragma unroll
    for (int i = 0; i < 16; ++i) {
      f32x4 hv = *(const f32x4*)&s_h[lane * 4 + i * 256];
      a += hv * W0[i];
      b += hv * W1[i];
    }
    float ra = __shfl(dpp_reduce63(a.x + a.y + a.z + a.w), 63);
    float rb = __shfl(dpp_reduce63(b.x + b.y + b.z + b.w), 63);
    // 6) fast tanh on lanes 0,1 in parallel; lane0 packs + publishes
    float pre = (lane == 0) ? (ra + bB0 + xpv.x) : (rb + bB1 + xpv.y);
    float hn  = fast_tanh(pre);
    float h1v = __shfl(hn, 1);
    if (lane == 0) {
      __hip_bfloat16 c0 = __float2bfloat16(hn);
      __hip_bfloat16 c1 = __float2bfloat16(h1v);
      uint32 word = (uint32)(*(u16*)&c0) | ((uint32)(*(u16*)&c1) << 16);
      word |= pubtag;
      __hip_atomic_store(hbdst + pidx, word, __ATOMIC_RELAXED,
                         __HIP_MEMORY_SCOPE_AGENT);    // fire-and-forget
    }
  };

  // ---------------- prologue: xp ring for t=0,1 ----------------------------
  float2 xpA = compute_xp(0);
  float2 xpB = compute_xp(1);

  // ---------------- the scan (unrolled x2: static ring/parity) -------------
  for (int t2 = 0; t2 < T_STEPS; t2 += 2) {
    const int g = (t2 >> 1) & 1;             // generation of h_t2 and h_{t2+1}
    const u64   expv  = g ? M64 : 0ull;
    const uint32 tagA = g ? TAGM32 : 0u;     // h_{t2+1} carries gen g
    const uint32 tagB = g ? 0u : TAGM32;     // h_{t2+2} carries gen !g

    step(t2,     hb0, hb1, expv, tagA, xpA);
    if (t2 + 2 < T_STEPS) xpA = compute_xp(t2 + 2);
    step(t2 + 1, hb1, hb0, expv, tagB, xpB);
    if (t2 + 3 < T_STEPS) xpB = compute_xp(t2 + 3);
  }

  // ---------------- output: sigmoid(hT @ Wo^T + bo) ------------------------
  {
    // h_2048: buffer hb0 (2048&1=0), generation (2048>>1)&1 = 0
    const uint32* src = hb0 + cbase;
    u64 u01 = 0, u23 = 0;
    bool d0 = false, d1 = false;
    for (;;) {
      if (!d0) {
        u01 = __hip_atomic_load((const u64*)src, __ATOMIC_RELAXED,
                                __HIP_MEMORY_SCOPE_AGENT);
        d0 = (u01 & M64) == 0ull;
      }
      if (!d1) {
        u23 = __hip_atomic_load((const u64*)(src + 2), __ATOMIC_RELAXED,
                                __HIP_MEMORY_SCOPE_AGENT);
        d1 = (u23 & M64) == 0ull;
      }
      if (__all(d0 && d1)) break;
      __builtin_amdgcn_s_sleep(1);
    }
    uint32 w0 = (uint32)u01 & ~TAGM32, w1 = (uint32)(u01 >> 32) & ~TAGM32;
    uint32 w2 = (uint32)u23 & ~TAGM32, w3 = (uint32)(u23 >> 32) & ~TAGM32;
    f32x4 pa, pb;
    pa.x = bits_to_f(w0 << 16);  pa.y = bits_to_f(w0 & 0xffff0000u);
    pa.z = bits_to_f(w1 << 16);  pa.w = bits_to_f(w1 & 0xffff0000u);
    pb.x = bits_to_f(w2 << 16);  pb.y = bits_to_f(w2 & 0xffff0000u);
    pb.z = bits_to_f(w3 << 16);  pb.w = bits_to_f(w3 & 0xffff0000u);
    *(f32x4*)&s_h[2 * cbase]     = pa;
    *(f32x4*)&s_h[2 * cbase + 4] = pb;
  }
  __syncthreads();
  {
    const int o = w * 8 + wv;     // 8 outputs per WG, one per wave
    const float* worow = wo_w + (size_t)o * HIDDEN_N + lane * 4;
    f32x4 acc = {0.f, 0.f, 0.f, 0.f};
#pragma unroll
    for (int k = 0; k < 16; ++k)
      acc += (*(const f32x4*)(worow + k * 256)) *
             (*(const f32x4*)&s_h[lane * 4 + k * 256]);
    float s = __shfl(dpp_reduce63(acc.x + acc.y + acc.z + acc.w), 63);
    if (lane == 0) {
      float z = s + wo_b[o];
      out[o] = 1.f / (1.f + expf(-z));
    }
  }
}

extern "C" void kernel_launch(void* const* d_in, const int* in_sizes, int n_in,
                              void* d_out, int out_size, void* d_ws,
                              size_t ws_size, hipStream_t stream) {
  const float* x    = (const float*)d_in[0];
  const float* wh_w = (const float*)d_in[1];
  const float* wh_b = (const float*)d_in[2];
  const float* wx_w = (const float*)d_in[3];
  const float* wx_b = (const float*)d_in[4];
  const float* wo_w = (const float*)d_in[5];
  const float* wo_b = (const float*)d_in[6];
  float* out = (float*)d_out;
  float* ws  = (float*)d_ws;

  // hb0 = 0x00 (h_0 = 0, generation 0, immediately valid at t=0);
  // hb1 = 0x40 bytes (generation-1 stale marker for t=1's gen-0 wait).
  hipMemsetAsync((char*)d_ws + 1024 * 4, 0x00, 2048 * 4, stream);
  hipMemsetAsync((char*)d_ws + 3072 * 4, 0x40, 2048 * 4, stream);

  hipLaunchKernelGGL(rnn_persistent, dim3(NWG), dim3(NTHR), 0, stream,
                     x, wh_w, wh_b, wx_w, wx_b, wo_w, wo_b, out, ws);
}